// Round 1
// 18992.795 us; speedup vs baseline: 1.1672x; 1.1672x over previous
//
#include <hip/hip_runtime.h>
#include <math.h>

typedef unsigned int u32;
typedef unsigned long long ull;
typedef float f4v __attribute__((ext_vector_type(4)));

#define T_     1024
#define N_     128
#define V_     35
#define H_     512
#define VS_    128
#define KS_    128
#define MAXLEN 250
#define NBLK   256

// ---- workspace layout (bytes) ----
#define OFF_TOKF   0          // u32[128]: ((step+1)<<8)|tok  (owner -> A-blocks)
#define OFF_H1F    512        // u32[8][32]: step+1 per A tile (A-blocks -> owner)
#define OFF_HFLAG  1536       // u32[128]  (owner -> helper)
#define OFF_PFLAG  2048       // u32[128]  (helper -> owner)
#define OFF_PMS    2560       // float[256] (m,s per n)
#define OFF_H2P    4096       // float[128*128]
#define OFF_PCTX   69632      // float[128*128]
#define OFF_VM     135168     // float[128*128]
#define OFF_EMBG   200704     // float[35*2048]  emb[tok] @ W_ih1[:, :512].T (permuted cols)
#define OFF_VMG    487424     // float[128*2048] vm @ W_ih1[:, 512:].T + b_ih1 + b_hh1
#define OFF_H1A    1536000    // float[128*512] ping
#define OFF_H1B    1798144    // float[128*512] pong
#define OFF_KT     2097152ull // optional key (n,t,128): 64MB
#define OFF_VT     69206016ull// optional val (n,t,128): 64MB
#define WS_T_NEED  136314880ull

#define ASF_STR 516           // 516 % 32 == 4: spreads LDS banks
#define WSBUF   4352          // 64*68 floats per Ws buffer (double-buffered)

__device__ __forceinline__ float sigf(float x){ return 1.0f/(1.0f+expf(-x)); }
__device__ __forceinline__ float dot4(float4 a, float4 b){ return a.x*b.x + a.y*b.y + a.z*b.z + a.w*b.w; }

// agent-scope (sc1) accessors: bypass stale L1/L2 for cross-block mutable state.
__device__ __forceinline__ float cohloadf(const float* p){
  return __hip_atomic_load(p, __ATOMIC_RELAXED, __HIP_MEMORY_SCOPE_AGENT);
}
__device__ __forceinline__ void cohstoref(float* p, float v){
  __hip_atomic_store(p, v, __ATOMIC_RELAXED, __HIP_MEMORY_SCOPE_AGENT);
}
__device__ __forceinline__ ull cohloadu(const ull* p){
  return __hip_atomic_load(p, __ATOMIC_RELAXED, __HIP_MEMORY_SCOPE_AGENT);
}
__device__ __forceinline__ u32 cohloadw(const u32* p){
  return __hip_atomic_load(p, __ATOMIC_RELAXED, __HIP_MEMORY_SCOPE_AGENT);
}
__device__ __forceinline__ void cohstorew(u32* p, u32 v){
  __hip_atomic_store(p, v, __ATOMIC_RELAXED, __HIP_MEMORY_SCOPE_AGENT);
}

// ---- one-time prep: values_mean + zero h1 ----
__global__ void prep_state(const float* __restrict__ val, char* __restrict__ ws){
  __shared__ float part[256];
  float* vmarr = (float*)(ws + OFF_VM);
  float* h1A   = (float*)(ws + OFF_H1A);
  const int n = blockIdx.x, tid = threadIdx.x;
  const int c = tid >> 7, v = tid & 127;
  float acc = 0.f;
  const float* vp = val + (size_t)(c*512)*N_*VS_ + (size_t)n*VS_ + v;
  #pragma unroll 8
  for (int t = 0; t < 512; ++t) acc += vp[(size_t)t*N_*VS_];
  part[tid] = acc;
  __syncthreads();
  if (tid < 128) vmarr[(size_t)n*128 + tid] = (part[tid] + part[tid+128]) * (1.0f/1024.0f);
  h1A[(size_t)n*H_ + tid]       = 0.f;
  h1A[(size_t)n*H_ + 256 + tid] = 0.f;
}

// embG[v][c] = sum_k emb[v][k] * W_ih1[(c&3)*512 + (c>>2)][k],  c = hid*4+gate (permuted)
__global__ void prep_embG(const float* __restrict__ emb, const float* __restrict__ W_ih1,
                          char* __restrict__ ws){
  float* embG = (float*)(ws + OFF_EMBG);
  const int v = blockIdx.x >> 3, cb = blockIdx.x & 7;
  const int c = cb*256 + threadIdx.x;
  const int row_w = (c & 3)*H_ + (c >> 2);
  const float4* w4 = (const float4*)(W_ih1 + (size_t)row_w*640);
  const float4* e4 = (const float4*)(emb + (size_t)v*H_);
  float s = 0.f;
  #pragma unroll 8
  for (int k = 0; k < 128; ++k) s += dot4(w4[k], e4[k]);
  embG[(size_t)v*2048 + c] = s;
}

// vmG[n][c] = sum_j vm[n][j] * W_ih1[row_w][512+j] + b_ih1[row_w] + b_hh1[row_w]
__global__ void prep_vmG(const float* __restrict__ W_ih1, const float* __restrict__ b_ih1,
                         const float* __restrict__ b_hh1, char* __restrict__ ws){
  float* vmG = (float*)(ws + OFF_VMG);
  const float* vmarr = (const float*)(ws + OFF_VM);
  const int n = blockIdx.x >> 3, cb = blockIdx.x & 7;
  const int c = cb*256 + threadIdx.x;
  const int row_w = (c & 3)*H_ + (c >> 2);
  const float4* w4 = (const float4*)(W_ih1 + (size_t)row_w*640 + 512);
  const float4* v4 = (const float4*)(vmarr + (size_t)n*128);
  float s = b_ih1[row_w] + b_hh1[row_w];
  #pragma unroll 8
  for (int k = 0; k < 32; ++k) s += dot4(w4[k], v4[k]);
  vmG[(size_t)n*2048 + c] = s;
}

// optional: key/val (t,n,128) -> (n,t,128) sequential per-chain streams
__global__ void prep_transpose(const float* __restrict__ key, const float* __restrict__ val,
                               char* __restrict__ ws){
  float* keyT = (float*)(ws + OFF_KT);
  float* valT = (float*)(ws + OFF_VT);
  const int bt = blockIdx.x & 1023;
  const bool isv = blockIdx.x >= 1024;
  const float* src = isv ? val : key;
  float* dst = isv ? valT : keyT;
  const int nn = threadIdx.x >> 1, hf = threadIdx.x & 1;
  const float4* s4 = (const float4*)(src + ((size_t)bt*N_ + nn)*KS_ + hf*64);
  float4* d4 = (float4*)(dst + ((size_t)nn*T_ + bt)*KS_ + hf*64);
  #pragma unroll
  for (int i = 0; i < 16; ++i) d4[i] = s4[i];
}

// ---- persistent decoder: 256 blocks x 256 threads, NO grid barriers ----
__global__ __launch_bounds__(256, 1) void decoder_main(
  const float* __restrict__ keyA, const float* __restrict__ valA,
  const ull nstr, const ull kstr,
  const int* __restrict__ lens,
  const float* __restrict__ W_hh1,
  const float* __restrict__ W_ih2, const float* __restrict__ W_hh2,
  const float* __restrict__ b_ih2, const float* __restrict__ b_hh2,
  const float* __restrict__ W_out, const float* __restrict__ b_out,
  float* __restrict__ out, char* __restrict__ ws)
{
  // Phase A: AsF[16][516] + Ws double buffer 2*[64][68]. Phase BC overlays front of AsF.
  __shared__ __align__(16) float smem[16*ASF_STR + 2*WSBUF];   // 16960 floats = 67.8KB
  __shared__ float c1_keep[256];
  __shared__ float h2_keep[128];
  __shared__ float c2_keep[128];
  __shared__ int   toksh[16];

  float* AsF = smem;
  float* WsB = smem + 16*ASF_STR;

  u32* tokflag = (u32*)(ws + OFF_TOKF);
  u32* h1flag  = (u32*)(ws + OFF_H1F);
  u32* hflag   = (u32*)(ws + OFF_HFLAG);
  u32* pflag   = (u32*)(ws + OFF_PFLAG);
  float* pms   = (float*)(ws + OFF_PMS);
  float* h2p   = (float*)(ws + OFF_H2P);
  float* pctx  = (float*)(ws + OFF_PCTX);
  float* embG  = (float*)(ws + OFF_EMBG);
  float* vmG   = (float*)(ws + OFF_VMG);
  float* h1cur = (float*)(ws + OFF_H1A);
  float* h1nxt = (float*)(ws + OFF_H1B);

  const int b = blockIdx.x, tid = threadIdx.x;

  c1_keep[tid] = 0.f;
  if (tid < 128){ h2_keep[tid] = 0.f; c2_keep[tid] = 0.f; }

  const int rt = b >> 5, ct = b & 31;
  const int row0 = rt*16, c0 = ct*64;
  const int lane = tid & 63, qw = tid >> 6;
  const int r_g = lane >> 4, c_g = lane & 15;
  const int c_st = tid >> 2, seg = tid & 3;
  const int sgl = c0 + c_st, shh = sgl >> 2, sgg = sgl & 3;
  const float* wsh = W_hh1 + (size_t)(sgg*H_ + shh)*H_ + seg*16;

  const int n = b & 127;
  const bool owner = (b < 128);

  #pragma unroll 1
  for (int step = 0; step < MAXLEN; ++step){
    // ============ Phase A: LSTM1 gates = h1 @ W_hh1.T + embG[tok] + vmG[n] ============
    {
      // prefetch chunk-0 weights (static, L2-resident)
      float4 w0 = ((const float4*)wsh)[0], w1 = ((const float4*)wsh)[1],
             w2 = ((const float4*)wsh)[2], w3 = ((const float4*)wsh)[3];

      // wait for our 16 rows' toks (implies h1_{s-1} of this tile is published)
      if (tid < 16){
        u32 tv;
        const u32 tgt = (u32)step << 8;
        while ((tv = cohloadw(&tokflag[row0 + tid])) < tgt) __builtin_amdgcn_s_sleep(1);
        toksh[tid] = (int)(tv & 255u);
      }
      __syncthreads();

      { // stage h1_{s-1} tile (16 x 512) via batched sc1 loads
        const int r = tid >> 4, sub = tid & 15;
        const ull* src = (const ull*)(h1cur + (size_t)(row0 + r)*H_ + sub*32);
        ull* dst = (ull*)(AsF + r*ASF_STR + sub*32);
        #pragma unroll
        for (int jj = 0; jj < 16; jj += 8){
          ull t0=cohloadu(src+jj+0), t1=cohloadu(src+jj+1), t2=cohloadu(src+jj+2),
              t3=cohloadu(src+jj+3), t4u=cohloadu(src+jj+4), t5=cohloadu(src+jj+5),
              t6=cohloadu(src+jj+6), t7=cohloadu(src+jj+7);
          dst[jj+0]=t0; dst[jj+1]=t1; dst[jj+2]=t2; dst[jj+3]=t3;
          dst[jj+4]=t4u; dst[jj+5]=t5; dst[jj+6]=t6; dst[jj+7]=t7;
        }
      }

      float acc[4][4];
      #pragma unroll
      for (int i = 0; i < 4; ++i){ acc[i][0]=0.f; acc[i][1]=0.f; acc[i][2]=0.f; acc[i][3]=0.f; }

      #pragma unroll 1
      for (int ch = 0; ch < 8; ++ch){
        float* W = WsB + (ch & 1)*WSBUF;
        { float* wd = W + c_st*68 + seg*16;
          ((float4*)wd)[0]=w0; ((float4*)wd)[1]=w1; ((float4*)wd)[2]=w2; ((float4*)wd)[3]=w3;
        }
        if (ch < 7){
          const float* p = wsh + (ch+1)*64;
          w0 = ((const float4*)p)[0]; w1 = ((const float4*)p)[1];
          w2 = ((const float4*)p)[2]; w3 = ((const float4*)p)[3];
        }
        __syncthreads();
        const int kbase = ch*64;
        #pragma unroll
        for (int kq = 0; kq < 4; ++kq){
          const int t4 = (qw*4 + kq)*4;
          float4 wv0 = *(const float4*)(W + (c_g   )*68 + t4);
          float4 wv1 = *(const float4*)(W + (c_g+16)*68 + t4);
          float4 wv2 = *(const float4*)(W + (c_g+32)*68 + t4);
          float4 wv3 = *(const float4*)(W + (c_g+48)*68 + t4);
          const int ko = kbase + t4;
          float4 av0 = *(const float4*)(AsF + (r_g   )*ASF_STR + ko);
          float4 av1 = *(const float4*)(AsF + (r_g+ 4)*ASF_STR + ko);
          float4 av2 = *(const float4*)(AsF + (r_g+ 8)*ASF_STR + ko);
          float4 av3 = *(const float4*)(AsF + (r_g+12)*ASF_STR + ko);
          acc[0][0]+=dot4(av0,wv0); acc[0][1]+=dot4(av0,wv1); acc[0][2]+=dot4(av0,wv2); acc[0][3]+=dot4(av0,wv3);
          acc[1][0]+=dot4(av1,wv0); acc[1][1]+=dot4(av1,wv1); acc[1][2]+=dot4(av1,wv2); acc[1][3]+=dot4(av1,wv3);
          acc[2][0]+=dot4(av2,wv0); acc[2][1]+=dot4(av2,wv1); acc[2][2]+=dot4(av2,wv2); acc[2][3]+=dot4(av2,wv3);
          acc[3][0]+=dot4(av3,wv0); acc[3][1]+=dot4(av3,wv1); acc[3][2]+=dot4(av3,wv2); acc[3][3]+=dot4(av3,wv3);
        }
      }
      __syncthreads();
      float* Red = WsB;   // [a(16)][q(4)][lane(64)] = 4096 floats
      #pragma unroll
      for (int ri = 0; ri < 4; ++ri)
        #pragma unroll
        for (int ci = 0; ci < 4; ++ci)
          Red[((ri*4+ci)*4 + qw)*64 + lane] = acc[ri][ci];
      __syncthreads();
      float* Gs = AsF;    // reuse, stride 68
      { const int l2 = tid & 63, g = tid >> 6;
        const int row_l = (l2 >> 4) + 4*g;
        const int nrow = row0 + row_l;
        const float* eg = embG + (size_t)toksh[row_l]*2048 + c0;
        const float* vg = vmG  + (size_t)nrow*2048 + c0;
        #pragma unroll
        for (int j = 0; j < 4; ++j){
          const int a = g*4 + j;
          const float* rp = Red + a*256 + l2;
          float s = rp[0] + rp[64] + rp[128] + rp[192];
          const int col_l = (l2 & 15) + 16*j;
          s += eg[col_l] + vg[col_l];
          Gs[row_l*68 + col_l] = s;
        }
      }
      __syncthreads();
      { const int r = tid >> 4, hl = tid & 15;
        float4 q = *(const float4*)(Gs + r*68 + hl*4);   // i,f,g,o
        const int row = row0 + r, hid = ct*16 + hl;
        float cold = c1_keep[tid];
        float cn = sigf(q.y)*cold + sigf(q.x)*tanhf(q.z);
        float hn = sigf(q.w)*tanhf(cn);
        c1_keep[tid] = cn;
        cohstoref(h1nxt + (size_t)row*H_ + hid, hn);
      }
      __syncthreads();   // drains sc1 h1 stores
      if (tid == 0) cohstorew(&h1flag[rt*32 + ct], (u32)(step+1));
    }

    // ============ Phase BC: pair (n, n+128); owner = b<128 ============
    {
      float* xs   = smem;          // [640] owner: [h1 | h2old]
      float* ctxL = smem + 640;    // [128] local unnorm ctx (reuses G2 space)
      float* G2   = smem + 640;    // [512] owner gate pre-acts
      float* h2s  = smem + 1152;   // [128]
      float* Es   = smem + 1280;   // [1024]
      float* red  = smem + 2304;   // [4+]
      float* Cs   = smem + 2560;   // [8][128]
      float* Zs   = smem + 3584;   // [256]
      float* Pr   = smem + 3840;   // [64]
      const int len = lens[n];
      const int mid = (7*len) >> 4;         // owner gets 7/16 (it also does LSTM2+output)
      const int lo = owner ? 0 : mid;
      const int hi = owner ? mid : len;

      if (owner){
        if (tid < 32){
          while (cohloadw(&h1flag[(n >> 4)*32 + tid]) < (u32)(step+1)) __builtin_amdgcn_s_sleep(1);
        }
        __syncthreads();
        xs[tid]       = cohloadf(h1nxt + (size_t)n*H_ + tid);
        xs[256 + tid] = cohloadf(h1nxt + (size_t)n*H_ + 256 + tid);
        if (tid < 128) xs[512 + tid] = h2_keep[tid];
        __syncthreads();
        { float fa = b_ih2[tid]     + b_hh2[tid];
          float fb = b_ih2[256+tid] + b_hh2[256+tid];
          const float4* wa = (const float4*)(W_ih2 + (size_t)tid*512);
          const float4* wb = (const float4*)(W_ih2 + (size_t)(256+tid)*512);
          const float4* xv4 = (const float4*)xs;
          #pragma unroll 8
          for (int k4 = 0; k4 < 128; ++k4){
            float4 xv = xv4[k4];
            fa += dot4(wa[k4], xv);
            fb += dot4(wb[k4], xv);
          }
          const float4* ha = (const float4*)(W_hh2 + (size_t)tid*128);
          const float4* hb = (const float4*)(W_hh2 + (size_t)(256+tid)*128);
          #pragma unroll 8
          for (int k4 = 0; k4 < 32; ++k4){
            float4 xv = xv4[128 + k4];
            fa += dot4(ha[k4], xv);
            fb += dot4(hb[k4], xv);
          }
          G2[tid] = fa; G2[256+tid] = fb;
        }
        __syncthreads();
        if (tid < 128){
          float gi = G2[tid], gf = G2[128+tid], gg = G2[256+tid], go = G2[384+tid];
          float cold = c2_keep[tid];
          float cn = sigf(gf)*cold + sigf(gi)*tanhf(gg);
          float hn = sigf(go)*tanhf(cn);
          c2_keep[tid] = cn; h2_keep[tid] = hn;
          h2s[tid] = hn;
          cohstoref(h2p + (size_t)n*128 + tid, hn);
        }
        __syncthreads();                         // drains sc1 stores
        if (tid == 0) cohstorew(&hflag[n], (u32)(step+1));
      } else {
        if (tid == 0){
          while (cohloadw(&hflag[n]) < (u32)(step+1)) __builtin_amdgcn_s_sleep(1);
        }
        __syncthreads();
        if (tid < 128) h2s[tid] = cohloadf(h2p + (size_t)n*128 + tid);
        __syncthreads();
      }

      // --- energies over [lo, hi) ---
      const float* krow = keyA + (size_t)n*nstr;
      for (int t = lo + tid; t < hi; t += 256){
        const float4* kp = (const float4*)(krow + (size_t)t*kstr);
        float e = 0.f;
        #pragma unroll
        for (int k4 = 0; k4 < 32; ++k4){
          float4 q = kp[k4];
          e += q.x*h2s[k4*4+0] + q.y*h2s[k4*4+1] + q.z*h2s[k4*4+2] + q.w*h2s[k4*4+3];
        }
        Es[t] = e;
      }
      __syncthreads();
      // --- local max via wave shuffles ---
      float lm = -3.0e38f;
      for (int t = lo + tid; t < hi; t += 256) lm = fmaxf(lm, Es[t]);
      #pragma unroll
      for (int off = 32; off > 0; off >>= 1) lm = fmaxf(lm, __shfl_xor(lm, off));
      if (lane == 0) red[qw] = lm;
      __syncthreads();
      const float m_l = fmaxf(fmaxf(red[0], red[1]), fmaxf(red[2], red[3]));
      __syncthreads();
      // --- exp + local sum ---
      float ls = 0.f;
      for (int t = lo + tid; t < hi; t += 256){ float p = expf(Es[t]-m_l); Es[t] = p; ls += p; }
      #pragma unroll
      for (int off = 32; off > 0; off >>= 1) ls += __shfl_xor(ls, off);
      if (lane == 0) red[qw] = ls;
      __syncthreads();
      const float s_l = red[0] + red[1] + red[2] + red[3];
      // --- unnormalized ctx partial ---
      const float* vrow = valA + (size_t)n*nstr;
      { const int part = tid >> 5, v4i = (tid & 31)*4;
        f4v a0 = {0.f,0.f,0.f,0.f}, a1 = a0, a2 = a0, a3 = a0;
        int t = lo + part;
        for (; t + 24 < hi; t += 32){
          float p0 = Es[t], p1 = Es[t+8], p2 = Es[t+16], p3 = Es[t+24];
          f4v u0 = *(const f4v*)(vrow + (size_t)(t    )*kstr + v4i);
          f4v u1 = *(const f4v*)(vrow + (size_t)(t+ 8 )*kstr + v4i);
          f4v u2 = *(const f4v*)(vrow + (size_t)(t+16 )*kstr + v4i);
          f4v u3 = *(const f4v*)(vrow + (size_t)(t+24 )*kstr + v4i);
          a0 += p0*u0; a1 += p1*u1; a2 += p2*u2; a3 += p3*u3;
        }
        for (; t < hi; t += 8){
          f4v u0 = *(const f4v*)(vrow + (size_t)t*kstr + v4i);
          a0 += Es[t]*u0;
        }
        f4v ctv = a0 + a1 + a2 + a3;
        Cs[part*128 + v4i+0]=ctv.x; Cs[part*128 + v4i+1]=ctv.y;
        Cs[part*128 + v4i+2]=ctv.z; Cs[part*128 + v4i+3]=ctv.w;
      }
      __syncthreads();
      if (tid < 128){
        float s = 0.f;
        #pragma unroll
        for (int p8 = 0; p8 < 8; ++p8) s += Cs[p8*128 + tid];
        ctxL[tid] = s;
      }
      __syncthreads();

      if (!owner){
        if (tid < 128) cohstoref(pctx + (size_t)n*128 + tid, ctxL[tid]);
        if (tid == 0){ cohstoref(pms + 2*n, m_l); cohstoref(pms + 2*n + 1, s_l); }
        __syncthreads();                          // drains sc1 stores
        if (tid == 0) cohstorew(&pflag[n], (u32)(step+1));
      } else {
        if (tid == 0){
          while (cohloadw(&pflag[n]) < (u32)(step+1)) __builtin_amdgcn_s_sleep(1);
        }
        __syncthreads();
        if (tid < 128){
          float m2 = cohloadf(pms + 2*n), s2v = cohloadf(pms + 2*n + 1);
          float c2v = cohloadf(pctx + (size_t)n*128 + tid);
          float m = fmaxf(m_l, m2);
          float e1 = expf(m_l - m), e2 = expf(m2 - m);
          float denom = e1*s_l + e2*s2v;
          Zs[tid]       = h2s[tid];
          Zs[128 + tid] = (e1*ctxL[tid] + e2*c2v) / denom;
        }
        __syncthreads();
        if (tid < V_){
          const float4* wr = (const float4*)(W_out + tid*256);
          float a = b_out[tid];
          #pragma unroll
          for (int k4 = 0; k4 < 64; ++k4){
            float4 q = wr[k4];
            a += q.x*Zs[k4*4+0] + q.y*Zs[k4*4+1] + q.z*Zs[k4*4+2] + q.w*Zs[k4*4+3];
          }
          Pr[tid] = a;
          out[((size_t)n*MAXLEN + step)*V_ + tid] = a;
        }
        __syncthreads();
        if (tid == 0){
          float bm = Pr[0]; int bi = 0;
          for (int v2 = 1; v2 < V_; ++v2){ float pv = Pr[v2]; if (pv > bm){ bm = pv; bi = v2; } }
          cohstorew(&tokflag[n], ((u32)(step+1) << 8) | (u32)bi);
        }
      }
    }
    __syncthreads();   // protect smem reuse by next step's Phase A
    float* tp = h1cur; h1cur = h1nxt; h1nxt = tp;
  }
}

extern "C" void kernel_launch(void* const* d_in, const int* in_sizes, int n_in,
                              void* d_out, int out_size, void* d_ws, size_t ws_size,
                              hipStream_t stream)
{
  const float* key    = (const float*)d_in[0];
  const float* val    = (const float*)d_in[1];
  const int*   lens   = (const int*)d_in[2];
  const float* emb    = (const float*)d_in[3];
  const float* W_ih1  = (const float*)d_in[4];
  const float* W_hh1  = (const float*)d_in[5];
  const float* b_ih1  = (const float*)d_in[6];
  const float* b_hh1  = (const float*)d_in[7];
  const float* W_ih2  = (const float*)d_in[8];
  const float* W_hh2  = (const float*)d_in[9];
  const float* b_ih2  = (const float*)d_in[10];
  const float* b_hh2  = (const float*)d_in[11];
  const float* W_out  = (const float*)d_in[12];
  const float* b_out  = (const float*)d_in[13];

  (void)in_sizes; (void)n_in; (void)out_size;

  (void)hipMemsetAsync(d_ws, 0, 4096, stream);   // all flags + pms
  prep_state<<<128, 256, 0, stream>>>(val, (char*)d_ws);
  prep_embG<<<280, 256, 0, stream>>>(emb, W_ih1, (char*)d_ws);
  prep_vmG<<<1024, 256, 0, stream>>>(W_ih1, b_ih1, b_hh1, (char*)d_ws);

  const int use_t = (ws_size >= WS_T_NEED) ? 1 : 0;
  const float* keyA = key; const float* valA = val;
  ull nstr = (ull)KS_, kstr = (ull)N_*KS_;
  if (use_t){
    prep_transpose<<<2048, 256, 0, stream>>>(key, val, (char*)d_ws);
    keyA = (const float*)((char*)d_ws + OFF_KT);
    valA = (const float*)((char*)d_ws + OFF_VT);
    nstr = (ull)T_*KS_; kstr = (ull)KS_;
  }

  decoder_main<<<NBLK, 256, 0, stream>>>(
      keyA, valA, nstr, kstr, lens, W_hh1,
      W_ih2, W_hh2, b_ih2, b_hh2, W_out, b_out,
      (float*)d_out, (char*)d_ws);
}

// Round 3
// 14413.768 us; speedup vs baseline: 1.5380x; 1.3177x over previous
//
#include <hip/hip_runtime.h>
#include <math.h>

typedef unsigned int u32;
typedef unsigned long long ull;
typedef float f4v __attribute__((ext_vector_type(4)));

#define T_     1024
#define N_     128
#define V_     35
#define H_     512
#define VS_    128
#define KS_    128
#define MAXLEN 250
#define NBLK   256

// ---- workspace layout (bytes) ----
#define OFF_TOKF   0          // u32[128]: ((step+1)<<8)|tok  (owner -> A-blocks)
#define OFF_H1F    512        // u32[8][32]: step+1 per A tile
#define OFF_H2OF   1536       // u32[128] owner-half-h2 flag
#define OFF_H2HF   2048       // u32[128] helper-half-h2 flag
#define OFF_PFLAG  2560       // u32[128] helper partial flag
#define OFF_PMS    3072       // float[256] (m,s per n)  -> zero region ends 4096
#define OFF_H2P    4096       // float[128*128]
#define OFF_PCTX   69632      // float[128*128]
#define OFF_VM     135168     // float[128*128]
#define OFF_EMBG   200704     // float[35*2048]
#define OFF_VMG    487424     // float[128*2048] (+biases folded)
#define OFF_H1A    1536000    // float[128*512] ping
#define OFF_H1B    1798144    // float[128*512] pong
#define OFF_W1P    2060288    // float[32*32768] pre-permuted W_hh1 staging blob (4MB)
#define OFF_W2TO   6254592    // float[640*256] owner-gate transposed W2
#define OFF_W2TH   6909952    // float[640*256] helper-gate transposed W2
#define OFF_B2O    7565312    // float[256]
#define OFF_B2H    7566336    // float[256]
#define OFF_WO2    7567360    // float[256*64] transposed W_out (padded V->64)
#define OFF_KT     8388608ull // optional key (n,t,128): 64MB
#define OFF_VT     75497472ull// optional val (n,t,128): 64MB
#define WS_T_NEED  142606336ull

#define ASF_STR 516           // LDS A-tile stride (%32==4)
#define WSBUF   4352          // 64*68 floats per Ws buffer (double-buffered)

__device__ __forceinline__ float sigf(float x){ return 1.0f/(1.0f+expf(-x)); }
__device__ __forceinline__ float dot4(float4 a, float4 b){ return a.x*b.x + a.y*b.y + a.z*b.z + a.w*b.w; }

__device__ __forceinline__ float cohloadf(const float* p){
  return __hip_atomic_load(p, __ATOMIC_RELAXED, __HIP_MEMORY_SCOPE_AGENT);
}
__device__ __forceinline__ void cohstoref(float* p, float v){
  __hip_atomic_store(p, v, __ATOMIC_RELAXED, __HIP_MEMORY_SCOPE_AGENT);
}
__device__ __forceinline__ ull cohloadu(const ull* p){
  return __hip_atomic_load(p, __ATOMIC_RELAXED, __HIP_MEMORY_SCOPE_AGENT);
}
__device__ __forceinline__ u32 cohloadw(const u32* p){
  return __hip_atomic_load(p, __ATOMIC_RELAXED, __HIP_MEMORY_SCOPE_AGENT);
}
__device__ __forceinline__ void cohstorew(u32* p, u32 v){
  __hip_atomic_store(p, v, __ATOMIC_RELAXED, __HIP_MEMORY_SCOPE_AGENT);
}

// ---- one-time prep: values_mean + zero h1 ----
__global__ void prep_state(const float* __restrict__ val, char* __restrict__ ws){
  __shared__ float part[256];
  float* vmarr = (float*)(ws + OFF_VM);
  float* h1A   = (float*)(ws + OFF_H1A);
  const int n = blockIdx.x, tid = threadIdx.x;
  const int c = tid >> 7, v = tid & 127;
  float acc = 0.f;
  const float* vp = val + (size_t)(c*512)*N_*VS_ + (size_t)n*VS_ + v;
  #pragma unroll 8
  for (int t = 0; t < 512; ++t) acc += vp[(size_t)t*N_*VS_];
  part[tid] = acc;
  __syncthreads();
  if (tid < 128) vmarr[(size_t)n*128 + tid] = (part[tid] + part[tid+128]) * (1.0f/1024.0f);
  h1A[(size_t)n*H_ + tid]       = 0.f;
  h1A[(size_t)n*H_ + 256 + tid] = 0.f;
}

// embG[v][c] = emb[v] . W_ih1 row (permuted c = hid*4+gate)
__global__ void prep_embG(const float* __restrict__ emb, const float* __restrict__ W_ih1,
                          char* __restrict__ ws){
  float* embG = (float*)(ws + OFF_EMBG);
  const int v = blockIdx.x >> 3, cb = blockIdx.x & 7;
  const int c = cb*256 + threadIdx.x;
  const int row_w = (c & 3)*H_ + (c >> 2);
  const float4* w4 = (const float4*)(W_ih1 + (size_t)row_w*640);
  const float4* e4 = (const float4*)(emb + (size_t)v*H_);
  float s = 0.f;
  #pragma unroll 8
  for (int k = 0; k < 128; ++k) s += dot4(w4[k], e4[k]);
  embG[(size_t)v*2048 + c] = s;
}

// vmG[n][c] = vm[n] . W_ih1[row][512:] + b_ih1[row] + b_hh1[row]
__global__ void prep_vmG(const float* __restrict__ W_ih1, const float* __restrict__ b_ih1,
                         const float* __restrict__ b_hh1, char* __restrict__ ws){
  float* vmG = (float*)(ws + OFF_VMG);
  const float* vmarr = (const float*)(ws + OFF_VM);
  const int n = blockIdx.x >> 3, cb = blockIdx.x & 7;
  const int c = cb*256 + threadIdx.x;
  const int row_w = (c & 3)*H_ + (c >> 2);
  const float4* w4 = (const float4*)(W_ih1 + (size_t)row_w*640 + 512);
  const float4* v4 = (const float4*)(vmarr + (size_t)n*128);
  float s = b_ih1[row_w] + b_hh1[row_w];
  #pragma unroll 8
  for (int k = 0; k < 32; ++k) s += dot4(w4[k], v4[k]);
  vmG[(size_t)n*2048 + c] = s;
}

// pre-permute W_hh1 into per-(ct,ch,j,tid) coalesced staging order
__global__ void prep_W1p(const float* __restrict__ W_hh1, char* __restrict__ ws){
  float* Wp1 = (float*)(ws + OFF_W1P);
  const int ct = blockIdx.x >> 3, ch = blockIdx.x & 7, tid = threadIdx.x;
  const int c_st = tid >> 2, seg = tid & 3;
  const int sgl = ct*64 + c_st, row_w = (sgl & 3)*H_ + (sgl >> 2);
  const float* src = W_hh1 + (size_t)row_w*H_ + ch*64 + seg*16;
  float* dstb = Wp1 + (size_t)ct*32768 + ch*4096 + tid*4;
  #pragma unroll
  for (int j = 0; j < 4; ++j)
    *(float4*)(dstb + j*1024) = *(const float4*)(src + j*4);
}

// W2T[k][c] split owner/helper (c = g*64+uu; owner unit uu, helper unit 64+uu), biases folded
__global__ void prep_W2T(const float* __restrict__ W_ih2, const float* __restrict__ W_hh2,
                         const float* __restrict__ b_ih2, const float* __restrict__ b_hh2,
                         char* __restrict__ ws){
  float* W2To = (float*)(ws + OFF_W2TO);
  float* W2Th = (float*)(ws + OFF_W2TH);
  const int k = blockIdx.x, tid = threadIdx.x;
  const int g = tid >> 6, uu = tid & 63;
  const int rowO = g*128 + uu, rowH = g*128 + 64 + uu;
  float vo, vh;
  if (k < 512){ vo = W_ih2[(size_t)rowO*512 + k]; vh = W_ih2[(size_t)rowH*512 + k]; }
  else        { vo = W_hh2[(size_t)rowO*128 + (k-512)]; vh = W_hh2[(size_t)rowH*128 + (k-512)]; }
  W2To[(size_t)k*256 + tid] = vo;
  W2Th[(size_t)k*256 + tid] = vh;
  if (k == 0){
    ((float*)(ws + OFF_B2O))[tid] = b_ih2[rowO] + b_hh2[rowO];
    ((float*)(ws + OFF_B2H))[tid] = b_ih2[rowH] + b_hh2[rowH];
  }
}

// Wo2[k][v] transposed output weights, padded to 64 cols
__global__ void prep_Wo2(const float* __restrict__ W_out, char* __restrict__ ws){
  float* Wo2 = (float*)(ws + OFF_WO2);
  const int idx = blockIdx.x*256 + threadIdx.x;   // 16384
  const int k = idx >> 6, v = idx & 63;
  Wo2[idx] = (v < V_) ? W_out[(size_t)v*256 + k] : 0.f;
}

// optional: key/val (t,n,128) -> (n,t,128)
__global__ void prep_transpose(const float* __restrict__ key, const float* __restrict__ val,
                               char* __restrict__ ws){
  float* keyT = (float*)(ws + OFF_KT);
  float* valT = (float*)(ws + OFF_VT);
  const int bt = blockIdx.x & 1023;
  const bool isv = blockIdx.x >= 1024;
  const float* src = isv ? val : key;
  float* dst = isv ? valT : keyT;
  const int nn = threadIdx.x >> 1, hf = threadIdx.x & 1;
  const float4* s4 = (const float4*)(src + ((size_t)bt*N_ + nn)*KS_ + hf*64);
  float4* d4 = (float4*)(dst + ((size_t)nn*T_ + bt)*KS_ + hf*64);
  #pragma unroll
  for (int i = 0; i < 16; ++i) d4[i] = s4[i];
}

// ---- persistent decoder: 256 blocks x 256 threads, flag-chained pipeline ----
__global__ __launch_bounds__(256, 1) void decoder_main(
  const float* __restrict__ keyA, const float* __restrict__ valA,
  const ull nstr, const ull kstr,
  const int* __restrict__ lens, const float* __restrict__ b_out,
  float* __restrict__ out, char* __restrict__ ws)
{
  __shared__ __align__(16) float smem[16*ASF_STR + 2*WSBUF];   // 16960 floats
  __shared__ float c1_keep[256];
  __shared__ float h2_keep[128];
  __shared__ float c2_keep[64];
  __shared__ int   toksh[16];

  float* AsF = smem;
  float* WsB = smem + 16*ASF_STR;

  u32* tokflag = (u32*)(ws + OFF_TOKF);
  u32* h1flag  = (u32*)(ws + OFF_H1F);
  u32* h2of    = (u32*)(ws + OFF_H2OF);
  u32* h2hf    = (u32*)(ws + OFF_H2HF);
  u32* pflag   = (u32*)(ws + OFF_PFLAG);
  float* pms   = (float*)(ws + OFF_PMS);
  float* h2p   = (float*)(ws + OFF_H2P);
  float* pctx  = (float*)(ws + OFF_PCTX);
  float* embG  = (float*)(ws + OFF_EMBG);
  float* vmG   = (float*)(ws + OFF_VMG);
  float* h1cur = (float*)(ws + OFF_H1A);
  float* h1nxt = (float*)(ws + OFF_H1B);
  const float* Wp1 = (const float*)(ws + OFF_W1P);
  const float* Wo2 = (const float*)(ws + OFF_WO2);

  const int b = blockIdx.x, tid = threadIdx.x;

  c1_keep[tid] = 0.f;
  if (tid < 128) h2_keep[tid] = 0.f;
  if (tid < 64)  c2_keep[tid] = 0.f;

  // Phase A constants
  const int rt = b >> 5, ct = b & 31;
  const int row0 = rt*16, c0 = ct*64;
  const int lane = tid & 63, qw = tid >> 6;
  const int r_g = lane >> 4, c_g = lane & 15;
  const int c_st = tid >> 2, seg = tid & 3;
  const float* wct = Wp1 + (size_t)ct*32768 + (tid << 2);

  // Phase BC constants
  const int n = b & 127;
  const bool owner = (b < 128);
  const float* W2T = (const float*)(ws + (owner ? OFF_W2TO : OFF_W2TH));
  const float* b2  = (const float*)(ws + (owner ? OFF_B2O : OFF_B2H));
  const int len = lens[n];
  const int mid = (7*len) >> 4;
  const int lo = owner ? 0 : mid;
  const int hi = owner ? mid : len;
  const float* krow = keyA + (size_t)n*nstr;
  const float* vrow = valA + (size_t)n*nstr;

  // BC LDS overlay (floats into smem)
  float* xs   = smem;          // [640]
  float* ctxL = smem + 640;    // [128] (reuses G2p space after GEMV)
  float* G2p  = smem + 640;    // [4*256]
  float* G2   = smem + 1664;   // [256]
  float* h2s  = smem + 1920;   // [128]
  float* Es   = smem + 2048;   // [1024]
  float* red  = smem + 3072;   // [64]
  float* Cs   = smem + 3136;   // [8*128]
  float* Zs   = smem + 4160;   // [256]
  float* Prp  = smem + 4416;   // [256]

  #pragma unroll 1
  for (int step = 0; step < MAXLEN; ++step){
    // ============ Phase A: LSTM1 gates = h1 @ W_hh1.T + embG[tok] + vmG[n] ============
    {
      float4 w0 = *(const float4*)(wct),
             w1 = *(const float4*)(wct+1024),
             w2 = *(const float4*)(wct+2048),
             w3 = *(const float4*)(wct+3072);

      if (tid < 16){
        u32 tv;
        const u32 tgt = (u32)step << 8;
        while ((tv = cohloadw(&tokflag[row0 + tid])) < tgt) __builtin_amdgcn_s_sleep(1);
        toksh[tid] = (int)(tv & 255u);
      }
      __syncthreads();

      { // stage h1 tile (16x512 = 32KB) flat-coalesced; row = 256 ull
        const ull* src = (const ull*)(h1cur + (size_t)row0*H_);
        ull* dstb = (ull*)AsF;
        #pragma unroll
        for (int i = 0; i < 16; ++i){
          const int u = tid + i*256;
          const int r = u >> 8, cc = u & 255;
          dstb[(size_t)r*258 + cc] = cohloadu(src + u);
        }
      }

      float acc[4][4];
      #pragma unroll
      for (int i = 0; i < 4; ++i){ acc[i][0]=0.f; acc[i][1]=0.f; acc[i][2]=0.f; acc[i][3]=0.f; }

      #pragma unroll 1
      for (int ch = 0; ch < 8; ++ch){
        float* W = WsB + (ch & 1)*WSBUF;
        { float* wd = W + c_st*68 + seg*16;
          ((float4*)wd)[0]=w0; ((float4*)wd)[1]=w1; ((float4*)wd)[2]=w2; ((float4*)wd)[3]=w3;
        }
        if (ch < 7){
          const float* q = wct + (ch+1)*4096;
          w0 = *(const float4*)(q);      w1 = *(const float4*)(q+1024);
          w2 = *(const float4*)(q+2048); w3 = *(const float4*)(q+3072);
        }
        __syncthreads();
        const int kbase = ch*64;
        #pragma unroll
        for (int kq = 0; kq < 4; ++kq){
          const int t4 = (qw*4 + kq)*4;
          float4 wv0 = *(const float4*)(W + (c_g   )*68 + t4);
          float4 wv1 = *(const float4*)(W + (c_g+16)*68 + t4);
          float4 wv2 = *(const float4*)(W + (c_g+32)*68 + t4);
          float4 wv3 = *(const float4*)(W + (c_g+48)*68 + t4);
          const int ko = kbase + t4;
          float4 av0 = *(const float4*)(AsF + (r_g   )*ASF_STR + ko);
          float4 av1 = *(const float4*)(AsF + (r_g+ 4)*ASF_STR + ko);
          float4 av2 = *(const float4*)(AsF + (r_g+ 8)*ASF_STR + ko);
          float4 av3 = *(const float4*)(AsF + (r_g+12)*ASF_STR + ko);
          acc[0][0]+=dot4(av0,wv0); acc[0][1]+=dot4(av0,wv1); acc[0][2]+=dot4(av0,wv2); acc[0][3]+=dot4(av0,wv3);
          acc[1][0]+=dot4(av1,wv0); acc[1][1]+=dot4(av1,wv1); acc[1][2]+=dot4(av1,wv2); acc[1][3]+=dot4(av1,wv3);
          acc[2][0]+=dot4(av2,wv0); acc[2][1]+=dot4(av2,wv1); acc[2][2]+=dot4(av2,wv2); acc[2][3]+=dot4(av2,wv3);
          acc[3][0]+=dot4(av3,wv0); acc[3][1]+=dot4(av3,wv1); acc[3][2]+=dot4(av3,wv2); acc[3][3]+=dot4(av3,wv3);
        }
        __syncthreads();
      }
      float* Red = WsB;   // [a(16)][q(4)][lane(64)]
      #pragma unroll
      for (int ri = 0; ri < 4; ++ri)
        #pragma unroll
        for (int ci = 0; ci < 4; ++ci)
          Red[((ri*4+ci)*4 + qw)*64 + lane] = acc[ri][ci];
      __syncthreads();
      float* Gs = AsF;    // reuse, stride 68
      { const int l2 = tid & 63, g = tid >> 6;
        const int row_l = (l2 >> 4) + 4*g;
        const int nrow = row0 + row_l;
        const float* eg = embG + (size_t)toksh[row_l]*2048 + c0;
        const float* vg = vmG  + (size_t)nrow*2048 + c0;
        #pragma unroll
        for (int j = 0; j < 4; ++j){
          const int a = g*4 + j;
          const float* rp = Red + a*256 + l2;
          float s = rp[0] + rp[64] + rp[128] + rp[192];
          const int col_l = (l2 & 15) + 16*j;
          s += eg[col_l] + vg[col_l];
          Gs[row_l*68 + col_l] = s;
        }
      }
      __syncthreads();
      { const int r = tid >> 4, hl = tid & 15;
        float4 q = *(const float4*)(Gs + r*68 + hl*4);   // i,f,g,o
        const int row = row0 + r, hid = ct*16 + hl;
        float cold = c1_keep[tid];
        float cn = sigf(q.y)*cold + sigf(q.x)*tanhf(q.z);
        float hn = sigf(q.w)*tanhf(cn);
        c1_keep[tid] = cn;
        cohstoref(h1nxt + (size_t)row*H_ + hid, hn);
      }
      __syncthreads();   // drains sc1 h1 stores
      if (tid == 0) cohstorew(&h1flag[rt*32 + ct], (u32)(step+1));
    }

    // ============ Phase B: LSTM2 split (owner: units 0..63, helper: 64..127) ============
    {
      if (tid < 32){
        while (cohloadw(&h1flag[(n >> 4)*32 + tid]) < (u32)(step+1)) __builtin_amdgcn_s_sleep(1);
      }
      __syncthreads();
      xs[tid]       = cohloadf(h1nxt + (size_t)n*H_ + tid);
      xs[256 + tid] = cohloadf(h1nxt + (size_t)n*H_ + 256 + tid);
      if (tid < 128) xs[512 + tid] = h2_keep[tid];
      __syncthreads();

      { // coalesced GEMV: 4 waves K-split, lane owns 4 gate-cols
        const int kw = tid >> 6, cl = tid & 63;
        const float* Wt = W2T + (size_t)kw*160*256 + cl*4;
        const float* xk = xs + kw*160;
        f4v acc = {0.f,0.f,0.f,0.f};
        #pragma unroll 4
        for (int k = 0; k < 160; ++k)
          acc += xk[k] * *(const f4v*)(Wt + (size_t)k*256);
        ((f4v*)(G2p + kw*256))[cl] = acc;
      }
      __syncthreads();
      G2[tid] = G2p[tid] + G2p[256+tid] + G2p[512+tid] + G2p[768+tid] + b2[tid];
      __syncthreads();
      if (tid < 64){
        const int unit = owner ? tid : (64 + tid);
        float gi = G2[tid], gf = G2[64+tid], gg = G2[128+tid], go = G2[192+tid];
        float cold = c2_keep[tid];
        float cn = sigf(gf)*cold + sigf(gi)*tanhf(gg);
        float hn = sigf(go)*tanhf(cn);
        c2_keep[tid] = cn;
        cohstoref(h2p + (size_t)n*128 + unit, hn);
      }
      __syncthreads();                              // drain sc1 half stores
      if (tid == 0){
        cohstorew(owner ? &h2of[n] : &h2hf[n], (u32)(step+1));
        u32* of = owner ? &h2hf[n] : &h2of[n];
        while (cohloadw(of) < (u32)(step+1)) __builtin_amdgcn_s_sleep(1);
      }
      __syncthreads();
      if (tid < 128){
        float hv = cohloadf(h2p + (size_t)n*128 + tid);
        h2s[tid] = hv; h2_keep[tid] = hv;
      }
      __syncthreads();
    }

    // ============ Phase C: attention split + (owner) merge/output ============
    {
      // energies: 16-lane group per t, coalesced key rows
      const float4* h2f = (const float4*)h2s;
      const int grp = tid >> 4, gj = tid & 15;
      const float4 hq0 = h2f[gj*2], hq1 = h2f[gj*2+1];
      for (int t = lo + grp; t < hi; t += 16){
        const float4* kp = (const float4*)(krow + (size_t)t*kstr + gj*8);
        float e = dot4(kp[0], hq0) + dot4(kp[1], hq1);
        e += __shfl_xor(e, 1); e += __shfl_xor(e, 2);
        e += __shfl_xor(e, 4); e += __shfl_xor(e, 8);
        if (gj == 0) Es[t] = e;
      }
      __syncthreads();
      // local max
      float lm = -3.0e38f;
      for (int t = lo + tid; t < hi; t += 256) lm = fmaxf(lm, Es[t]);
      #pragma unroll
      for (int off = 32; off > 0; off >>= 1) lm = fmaxf(lm, __shfl_xor(lm, off));
      if (lane == 0) red[qw] = lm;
      __syncthreads();
      const float m_l = fmaxf(fmaxf(red[0], red[1]), fmaxf(red[2], red[3]));
      __syncthreads();
      // exp + local sum
      float ls = 0.f;
      for (int t = lo + tid; t < hi; t += 256){ float p = expf(Es[t]-m_l); Es[t] = p; ls += p; }
      #pragma unroll
      for (int off = 32; off > 0; off >>= 1) ls += __shfl_xor(ls, off);
      if (lane == 0) red[qw] = ls;
      __syncthreads();
      const float s_l = red[0] + red[1] + red[2] + red[3];
      // unnormalized ctx partial (coalesced half-wave rows)
      { const int part = tid >> 5, v4i = (tid & 31)*4;
        f4v a0 = {0.f,0.f,0.f,0.f}, a1 = a0, a2 = a0, a3 = a0;
        int t = lo + part;
        for (; t + 24 < hi; t += 32){
          float p0 = Es[t], p1 = Es[t+8], p2 = Es[t+16], p3 = Es[t+24];
          f4v u0 = *(const f4v*)(vrow + (size_t)(t    )*kstr + v4i);
          f4v u1 = *(const f4v*)(vrow + (size_t)(t+ 8 )*kstr + v4i);
          f4v u2 = *(const f4v*)(vrow + (size_t)(t+16 )*kstr + v4i);
          f4v u3 = *(const f4v*)(vrow + (size_t)(t+24 )*kstr + v4i);
          a0 += p0*u0; a1 += p1*u1; a2 += p2*u2; a3 += p3*u3;
        }
        for (; t < hi; t += 8){
          f4v u0 = *(const f4v*)(vrow + (size_t)t*kstr + v4i);
          a0 += Es[t]*u0;
        }
        f4v ctv = a0 + a1 + a2 + a3;
        Cs[part*128 + v4i+0]=ctv.x; Cs[part*128 + v4i+1]=ctv.y;
        Cs[part*128 + v4i+2]=ctv.z; Cs[part*128 + v4i+3]=ctv.w;
      }
      __syncthreads();
      if (tid < 128){
        float s = 0.f;
        #pragma unroll
        for (int p8 = 0; p8 < 8; ++p8) s += Cs[p8*128 + tid];
        ctxL[tid] = s;
      }
      __syncthreads();

      if (!owner){
        if (tid < 128) cohstoref(pctx + (size_t)n*128 + tid, ctxL[tid]);
        if (tid == 0){ cohstoref(pms + 2*n, m_l); cohstoref(pms + 2*n + 1, s_l); }
        __syncthreads();                            // drain sc1 stores
        if (tid == 0) cohstorew(&pflag[n], (u32)(step+1));
      } else {
        if (tid == 0){
          while (cohloadw(&pflag[n]) < (u32)(step+1)) __builtin_amdgcn_s_sleep(1);
        }
        __syncthreads();
        if (tid < 128){
          float m2 = cohloadf(pms + 2*n), s2v = cohloadf(pms + 2*n + 1);
          float c2v = cohloadf(pctx + (size_t)n*128 + tid);
          float m = fmaxf(m_l, m2);
          float e1 = expf(m_l - m), e2 = expf(m2 - m);
          float denom = e1*s_l + e2*s2v;
          Zs[tid]       = h2s[tid];
          Zs[128 + tid] = (e1*ctxL[tid] + e2*c2v) / denom;
        }
        __syncthreads();
        { // output GEMM: transposed Wo2, 4-wave K-split
          const int kw = tid >> 6, lv = tid & 63;
          const float* wp = Wo2 + (size_t)kw*64*64 + lv;
          const float* zk = Zs + kw*64;
          float a = 0.f;
          #pragma unroll 8
          for (int k = 0; k < 64; ++k) a += zk[k]*wp[(size_t)k*64];
          Prp[kw*64 + lv] = a;
        }
        __syncthreads();
        if (tid < 64){
          float s = Prp[tid] + Prp[64+tid] + Prp[128+tid] + Prp[192+tid];
          float av = (tid < V_) ? (s + b_out[tid]) : -3.0e38f;
          if (tid < V_) out[((size_t)n*MAXLEN + step)*V_ + tid] = av;
          float bv = av; int bi = tid;
          #pragma unroll
          for (int off = 32; off > 0; off >>= 1){
            float ov = __shfl_xor(bv, off);
            int   oi = __shfl_xor(bi, off);
            if (ov > bv || (ov == bv && oi < bi)){ bv = ov; bi = oi; }
          }
          if (tid == 0) cohstorew(&tokflag[n], ((u32)(step+1) << 8) | (u32)bi);
        }
      }
    }
    __syncthreads();   // protect smem reuse by next step's Phase A
    float* tp = h1cur; h1cur = h1nxt; h1nxt = tp;
  }
}

extern "C" void kernel_launch(void* const* d_in, const int* in_sizes, int n_in,
                              void* d_out, int out_size, void* d_ws, size_t ws_size,
                              hipStream_t stream)
{
  const float* key    = (const float*)d_in[0];
  const float* val    = (const float*)d_in[1];
  const int*   lens   = (const int*)d_in[2];
  const float* emb    = (const float*)d_in[3];
  const float* W_ih1  = (const float*)d_in[4];
  const float* W_hh1  = (const float*)d_in[5];
  const float* b_ih1  = (const float*)d_in[6];
  const float* b_hh1  = (const float*)d_in[7];
  const float* W_ih2  = (const float*)d_in[8];
  const float* W_hh2  = (const float*)d_in[9];
  const float* b_ih2  = (const float*)d_in[10];
  const float* b_hh2  = (const float*)d_in[11];
  const float* W_out  = (const float*)d_in[12];
  const float* b_out  = (const float*)d_in[13];

  (void)in_sizes; (void)n_in; (void)out_size;

  (void)hipMemsetAsync(d_ws, 0, 4096, stream);   // flags + pms
  prep_state<<<128, 256, 0, stream>>>(val, (char*)d_ws);
  prep_embG<<<280, 256, 0, stream>>>(emb, W_ih1, (char*)d_ws);
  prep_vmG<<<1024, 256, 0, stream>>>(W_ih1, b_ih1, b_hh1, (char*)d_ws);
  prep_W1p<<<256, 256, 0, stream>>>(W_hh1, (char*)d_ws);
  prep_W2T<<<640, 256, 0, stream>>>(W_ih2, W_hh2, b_ih2, b_hh2, (char*)d_ws);
  prep_Wo2<<<64, 256, 0, stream>>>(W_out, (char*)d_ws);

  const int use_t = (ws_size >= WS_T_NEED) ? 1 : 0;
  const float* keyA = key; const float* valA = val;
  ull nstr = (ull)KS_, kstr = (ull)N_*KS_;
  if (use_t){
    prep_transpose<<<2048, 256, 0, stream>>>(key, val, (char*)d_ws);
    keyA = (const float*)((char*)d_ws + OFF_KT);
    valA = (const float*)((char*)d_ws + OFF_VT);
    nstr = (ull)T_*KS_; kstr = (ull)KS_;
  }

  decoder_main<<<NBLK, 256, 0, stream>>>(
      keyA, valA, nstr, kstr, lens, b_out,
      (float*)d_out, (char*)d_ws);
}

// Round 5
// 12612.298 us; speedup vs baseline: 1.7577x; 1.1428x over previous
//
#include <hip/hip_runtime.h>
#include <math.h>

typedef unsigned int u32;
typedef unsigned long long ull;
typedef float f4v __attribute__((ext_vector_type(4)));

#define T_     1024
#define N_     128
#define V_     35
#define H_     512
#define VS_    128
#define KS_    128
#define MAXLEN 250

// ---- workspace layout (bytes) ----
#define OFF_TOKF   0          // u32[128]: ((step+1)<<8)|tok  (owner -> A-blocks)
#define OFF_H1F    512        // u32[8][32]: step+1 per A tile
#define OFF_H2OF   1536       // u32[128] owner-half-h2 flag
#define OFF_H2HF   2048       // u32[128] helper1-half-h2 flag
#define OFF_PFLAG  2560       // u32[3][128] helper partial flags
#define OFF_PMS    4096       // float[3][256] (m,s per n per helper)
#define OFF_H2P    8192       // float[128*128] -> 73728
#define OFF_PCTX   73728      // float[3][128][128] -> 270336
#define OFF_VM     270336     // float[128*128] -> 335872
#define OFF_EMBG   335872     // float[35*2048] -> 622592
#define OFF_VMG    622592     // float[128*2048] -> 1671168
#define OFF_H1A    1671168    // float[128*512] ping -> 1933312
#define OFF_H1B    1933312    // float[128*512] pong -> 2195456
#define OFF_W1P    2195456    // float[32*32768] pre-permuted W_hh1 (4MB) -> 6389760
#define OFF_W2TO   6389760    // float[640*256] -> 7045120
#define OFF_W2TH   7045120    // float[640*256] -> 7700480
#define OFF_B2O    7700480    // float[256]
#define OFF_B2H    7701504    // float[256]
#define OFF_WO2    7702528    // float[256*64] -> 7768064
#define OFF_KT     8388608ull // key (n,t,128): 64MB
#define OFF_VT     75497472ull// val (n,t,128): 64MB
#define WS_T_NEED  142606336ull

#define ASF_STR 516           // LDS A-tile stride (%32==4)
#define WSBUF   4352          // 64*68 floats per Ws buffer (double-buffered)

__device__ __forceinline__ float sigf(float x){ return 1.0f/(1.0f+expf(-x)); }
__device__ __forceinline__ float dot4(float4 a, float4 b){ return a.x*b.x + a.y*b.y + a.z*b.z + a.w*b.w; }

__device__ __forceinline__ float cohloadf(const float* p){
  return __hip_atomic_load(p, __ATOMIC_RELAXED, __HIP_MEMORY_SCOPE_AGENT);
}
__device__ __forceinline__ void cohstoref(float* p, float v){
  __hip_atomic_store(p, v, __ATOMIC_RELAXED, __HIP_MEMORY_SCOPE_AGENT);
}
__device__ __forceinline__ ull cohloadu(const ull* p){
  return __hip_atomic_load(p, __ATOMIC_RELAXED, __HIP_MEMORY_SCOPE_AGENT);
}
__device__ __forceinline__ u32 cohloadw(const u32* p){
  return __hip_atomic_load(p, __ATOMIC_RELAXED, __HIP_MEMORY_SCOPE_AGENT);
}
__device__ __forceinline__ void cohstorew(u32* p, u32 v){
  __hip_atomic_store(p, v, __ATOMIC_RELAXED, __HIP_MEMORY_SCOPE_AGENT);
}

// ---- one-time prep: values_mean + zero h1 ----
__global__ void prep_state(const float* __restrict__ val, char* __restrict__ ws){
  __shared__ float part[256];
  float* vmarr = (float*)(ws + OFF_VM);
  float* h1A   = (float*)(ws + OFF_H1A);
  const int n = blockIdx.x, tid = threadIdx.x;
  const int c = tid >> 7, v = tid & 127;
  float acc = 0.f;
  const float* vp = val + (size_t)(c*512)*N_*VS_ + (size_t)n*VS_ + v;
  #pragma unroll 8
  for (int t = 0; t < 512; ++t) acc += vp[(size_t)t*N_*VS_];
  part[tid] = acc;
  __syncthreads();
  if (tid < 128) vmarr[(size_t)n*128 + tid] = (part[tid] + part[tid+128]) * (1.0f/1024.0f);
  h1A[(size_t)n*H_ + tid]       = 0.f;
  h1A[(size_t)n*H_ + 256 + tid] = 0.f;
}

// embG[v][c] = emb[v] . W_ih1 row (permuted c = hid*4+gate)
__global__ void prep_embG(const float* __restrict__ emb, const float* __restrict__ W_ih1,
                          char* __restrict__ ws){
  float* embG = (float*)(ws + OFF_EMBG);
  const int v = blockIdx.x >> 3, cb = blockIdx.x & 7;
  const int c = cb*256 + threadIdx.x;
  const int row_w = (c & 3)*H_ + (c >> 2);
  const float4* w4 = (const float4*)(W_ih1 + (size_t)row_w*640);
  const float4* e4 = (const float4*)(emb + (size_t)v*H_);
  float s = 0.f;
  #pragma unroll 8
  for (int k = 0; k < 128; ++k) s += dot4(w4[k], e4[k]);
  embG[(size_t)v*2048 + c] = s;
}

// vmG[n][c] = vm[n] . W_ih1[row][512:] + b_ih1[row] + b_hh1[row]
__global__ void prep_vmG(const float* __restrict__ W_ih1, const float* __restrict__ b_ih1,
                         const float* __restrict__ b_hh1, char* __restrict__ ws){
  float* vmG = (float*)(ws + OFF_VMG);
  const float* vmarr = (const float*)(ws + OFF_VM);
  const int n = blockIdx.x >> 3, cb = blockIdx.x & 7;
  const int c = cb*256 + threadIdx.x;
  const int row_w = (c & 3)*H_ + (c >> 2);
  const float4* w4 = (const float4*)(W_ih1 + (size_t)row_w*640 + 512);
  const float4* v4 = (const float4*)(vmarr + (size_t)n*128);
  float s = b_ih1[row_w] + b_hh1[row_w];
  #pragma unroll 8
  for (int k = 0; k < 32; ++k) s += dot4(w4[k], v4[k]);
  vmG[(size_t)n*2048 + c] = s;
}

// pre-permute W_hh1 into per-(ct,ch,j,tid) coalesced staging order
__global__ void prep_W1p(const float* __restrict__ W_hh1, char* __restrict__ ws){
  float* Wp1 = (float*)(ws + OFF_W1P);
  const int ct = blockIdx.x >> 3, ch = blockIdx.x & 7, tid = threadIdx.x;
  const int c_st = tid >> 2, seg = tid & 3;
  const int sgl = ct*64 + c_st, row_w = (sgl & 3)*H_ + (sgl >> 2);
  const float* src = W_hh1 + (size_t)row_w*H_ + ch*64 + seg*16;
  float* dstb = Wp1 + (size_t)ct*32768 + ch*4096 + tid*4;
  #pragma unroll
  for (int j = 0; j < 4; ++j)
    *(float4*)(dstb + j*1024) = *(const float4*)(src + j*4);
}

// W2T[k][c] split owner/helper (c = g*64+uu), biases folded
__global__ void prep_W2T(const float* __restrict__ W_ih2, const float* __restrict__ W_hh2,
                         const float* __restrict__ b_ih2, const float* __restrict__ b_hh2,
                         char* __restrict__ ws){
  float* W2To = (float*)(ws + OFF_W2TO);
  float* W2Th = (float*)(ws + OFF_W2TH);
  const int k = blockIdx.x, tid = threadIdx.x;
  const int g = tid >> 6, uu = tid & 63;
  const int rowO = g*128 + uu, rowH = g*128 + 64 + uu;
  float vo, vh;
  if (k < 512){ vo = W_ih2[(size_t)rowO*512 + k]; vh = W_ih2[(size_t)rowH*512 + k]; }
  else        { vo = W_hh2[(size_t)rowO*128 + (k-512)]; vh = W_hh2[(size_t)rowH*128 + (k-512)]; }
  W2To[(size_t)k*256 + tid] = vo;
  W2Th[(size_t)k*256 + tid] = vh;
  if (k == 0){
    ((float*)(ws + OFF_B2O))[tid] = b_ih2[rowO] + b_hh2[rowO];
    ((float*)(ws + OFF_B2H))[tid] = b_ih2[rowH] + b_hh2[rowH];
  }
}

// Wo2[k][v] transposed output weights, padded to 64 cols
__global__ void prep_Wo2(const float* __restrict__ W_out, char* __restrict__ ws){
  float* Wo2 = (float*)(ws + OFF_WO2);
  const int idx = blockIdx.x*256 + threadIdx.x;   // 16384
  const int k = idx >> 6, v = idx & 63;
  Wo2[idx] = (v < V_) ? W_out[(size_t)v*256 + k] : 0.f;
}

// key/val (t,n,128) -> (n,t,128)
__global__ void prep_transpose(const float* __restrict__ key, const float* __restrict__ val,
                               char* __restrict__ ws){
  float* keyT = (float*)(ws + OFF_KT);
  float* valT = (float*)(ws + OFF_VT);
  const int bt = blockIdx.x & 1023;
  const bool isv = blockIdx.x >= 1024;
  const float* src = isv ? val : key;
  float* dst = isv ? valT : keyT;
  const int nn = threadIdx.x >> 1, hf = threadIdx.x & 1;
  const float4* s4 = (const float4*)(src + ((size_t)bt*N_ + nn)*KS_ + hf*64);
  float4* d4 = (float4*)(dst + ((size_t)nn*T_ + bt)*KS_ + hf*64);
  #pragma unroll
  for (int i = 0; i < 16; ++i) d4[i] = s4[i];
}

// ---- persistent decoder: grid = 128*(nsplit) blocks x 256 threads ----
// roleIdx = b>>7: 0 owner (A/B + attn + merge), 1 helper1 (A/B + attn),
//                 2,3 pure attention helpers (only when nsplit==4).
__global__ __launch_bounds__(256, 1) void decoder_main(
  const float* __restrict__ keyA, const float* __restrict__ valA,
  const ull nstr, const ull kstr, const int nsplit,
  const int* __restrict__ lens, const float* __restrict__ b_out,
  float* __restrict__ out, char* __restrict__ ws)
{
  __shared__ __align__(16) float smem[16*ASF_STR + 2*WSBUF];   // 16960 floats
  __shared__ float c1_keep[256];
  __shared__ float h2_keep[128];
  __shared__ float c2_keep[64];
  __shared__ int   toksh[16];

  float* AsF = smem;
  float* WsB = smem + 16*ASF_STR;

  u32* tokflag = (u32*)(ws + OFF_TOKF);
  u32* h1flag  = (u32*)(ws + OFF_H1F);
  u32* h2of    = (u32*)(ws + OFF_H2OF);
  u32* h2hf    = (u32*)(ws + OFF_H2HF);
  u32* pflag   = (u32*)(ws + OFF_PFLAG);
  float* pms   = (float*)(ws + OFF_PMS);
  float* h2p   = (float*)(ws + OFF_H2P);
  float* pctx  = (float*)(ws + OFF_PCTX);
  float* embG  = (float*)(ws + OFF_EMBG);
  float* vmG   = (float*)(ws + OFF_VMG);
  float* h1cur = (float*)(ws + OFF_H1A);
  float* h1nxt = (float*)(ws + OFF_H1B);
  const float* Wp1 = (const float*)(ws + OFF_W1P);
  const float* Wo2 = (const float*)(ws + OFF_WO2);

  const int b = blockIdx.x, tid = threadIdx.x;
  const int roleIdx = b >> 7;
  const int n = b & 127;
  const bool owner = (roleIdx == 0);
  const bool isAB  = (b < 256);

  c1_keep[tid] = 0.f;
  if (tid < 128) h2_keep[tid] = 0.f;
  if (tid < 64)  c2_keep[tid] = 0.f;

  // Phase A constants (valid for b<256)
  const int rt = b >> 5, ct = b & 31;
  const int row0 = (rt & 7)*16, c0 = ct*64;
  const int lane = tid & 63, qw = tid >> 6;
  const int r_g = lane >> 4, c_g = lane & 15;
  const int c_st = tid >> 2, seg = tid & 3;
  const float* wct = Wp1 + (size_t)ct*32768 + (tid << 2);

  // Phase BC constants
  const float* W2T = (const float*)(ws + (owner ? OFF_W2TO : OFF_W2TH));
  const float* b2  = (const float*)(ws + (owner ? OFF_B2O : OFF_B2H));
  const int len = lens[n];
  int w0i, w1i;
  if (nsplit == 4){
    w0i = (roleIdx==0) ? 0 : (roleIdx==1) ? 6 : (roleIdx==2) ? 15 : 24;
    w1i = (roleIdx==0) ? 6 : (roleIdx==1) ? 15 : (roleIdx==2) ? 24 : 32;
  } else {
    w0i = (roleIdx==0) ? 0 : 14;
    w1i = (roleIdx==0) ? 14 : 32;
  }
  const int lo = (len*w0i) >> 5;
  const int hi = (len*w1i) >> 5;     // last role: (len*32)>>5 == len exactly
  const float* krow = keyA + (size_t)n*nstr;
  const float* vrow = valA + (size_t)n*nstr;

  // BC LDS overlay (floats into smem)
  float* xs   = smem;          // [640]
  float* ctxL = smem + 640;    // [128] (reuses G2p space after GEMV)
  float* G2p  = smem + 640;    // [4*256]
  float* G2   = smem + 1664;   // [256]
  float* h2s  = smem + 1920;   // [128]
  float* Es   = smem + 2048;   // [1024]
  float* red  = smem + 3072;   // [64]
  float* Cs   = smem + 3136;   // [8*128]
  float* Zs   = smem + 4160;   // [256]
  float* Prp  = smem + 4416;   // [256]

  #pragma unroll 1
  for (int step = 0; step < MAXLEN; ++step){
    // ============ Phase A (b<256): LSTM1 gates = h1 @ W_hh1.T + embG + vmG ============
    if (isAB){
      float4 w0 = *(const float4*)(wct),
             w1 = *(const float4*)(wct+1024),
             w2 = *(const float4*)(wct+2048),
             w3 = *(const float4*)(wct+3072);

      if (tid < 16){
        u32 tv;
        const u32 tgt = (u32)step << 8;
        while ((tv = cohloadw(&tokflag[row0 + tid])) < tgt) __builtin_amdgcn_s_sleep(1);
        toksh[tid] = (int)(tv & 255u);
      }
      __syncthreads();

      { // stage h1 tile (16x512 = 32KB) flat-coalesced; row = 256 ull
        const ull* src = (const ull*)(h1cur + (size_t)row0*H_);
        ull* dstb = (ull*)AsF;
        #pragma unroll
        for (int i = 0; i < 16; ++i){
          const int u = tid + i*256;
          const int r = u >> 8, cc = u & 255;
          dstb[(size_t)r*258 + cc] = cohloadu(src + u);
        }
      }

      float acc[4][4];
      #pragma unroll
      for (int i = 0; i < 4; ++i){ acc[i][0]=0.f; acc[i][1]=0.f; acc[i][2]=0.f; acc[i][3]=0.f; }

      #pragma unroll 1
      for (int ch = 0; ch < 8; ++ch){
        float* W = WsB + (ch & 1)*WSBUF;
        { float* wd = W + c_st*68 + seg*16;
          ((float4*)wd)[0]=w0; ((float4*)wd)[1]=w1; ((float4*)wd)[2]=w2; ((float4*)wd)[3]=w3;
        }
        if (ch < 7){
          const float* q = wct + (ch+1)*4096;
          w0 = *(const float4*)(q);      w1 = *(const float4*)(q+1024);
          w2 = *(const float4*)(q+2048); w3 = *(const float4*)(q+3072);
        }
        __syncthreads();
        const int kbase = ch*64;
        #pragma unroll
        for (int kq = 0; kq < 4; ++kq){
          const int t4 = (qw*4 + kq)*4;
          float4 wv0 = *(const float4*)(W + (c_g   )*68 + t4);
          float4 wv1 = *(const float4*)(W + (c_g+16)*68 + t4);
          float4 wv2 = *(const float4*)(W + (c_g+32)*68 + t4);
          float4 wv3 = *(const float4*)(W + (c_g+48)*68 + t4);
          const int ko = kbase + t4;
          float4 av0 = *(const float4*)(AsF + (r_g   )*ASF_STR + ko);
          float4 av1 = *(const float4*)(AsF + (r_g+ 4)*ASF_STR + ko);
          float4 av2 = *(const float4*)(AsF + (r_g+ 8)*ASF_STR + ko);
          float4 av3 = *(const float4*)(AsF + (r_g+12)*ASF_STR + ko);
          acc[0][0]+=dot4(av0,wv0); acc[0][1]+=dot4(av0,wv1); acc[0][2]+=dot4(av0,wv2); acc[0][3]+=dot4(av0,wv3);
          acc[1][0]+=dot4(av1,wv0); acc[1][1]+=dot4(av1,wv1); acc[1][2]+=dot4(av1,wv2); acc[1][3]+=dot4(av1,wv3);
          acc[2][0]+=dot4(av2,wv0); acc[2][1]+=dot4(av2,wv1); acc[2][2]+=dot4(av2,wv2); acc[2][3]+=dot4(av2,wv3);
          acc[3][0]+=dot4(av3,wv0); acc[3][1]+=dot4(av3,wv1); acc[3][2]+=dot4(av3,wv2); acc[3][3]+=dot4(av3,wv3);
        }
        __syncthreads();
      }
      float* Red = WsB;   // [a(16)][q(4)][lane(64)]
      #pragma unroll
      for (int ri = 0; ri < 4; ++ri)
        #pragma unroll
        for (int ci = 0; ci < 4; ++ci)
          Red[((ri*4+ci)*4 + qw)*64 + lane] = acc[ri][ci];
      __syncthreads();
      float* Gs = AsF;    // reuse, stride 68
      { const int l2 = tid & 63, g = tid >> 6;
        const int row_l = (l2 >> 4) + 4*g;
        const int nrow = row0 + row_l;
        const float* eg = embG + (size_t)toksh[row_l]*2048 + c0;
        const float* vg = vmG  + (size_t)nrow*2048 + c0;
        #pragma unroll
        for (int j = 0; j < 4; ++j){
          const int a = g*4 + j;
          const float* rp = Red + a*256 + l2;
          float s = rp[0] + rp[64] + rp[128] + rp[192];
          const int col_l = (l2 & 15) + 16*j;
          s += eg[col_l] + vg[col_l];
          Gs[row_l*68 + col_l] = s;
        }
      }
      __syncthreads();
      { const int r = tid >> 4, hl = tid & 15;
        float4 q = *(const float4*)(Gs + r*68 + hl*4);   // i,f,g,o
        const int row = row0 + r, hid = ct*16 + hl;
        float cold = c1_keep[tid];
        float cn = sigf(q.y)*cold + sigf(q.x)*tanhf(q.z);
        float hn = sigf(q.w)*tanhf(cn);
        c1_keep[tid] = cn;
        cohstoref(h1nxt + (size_t)row*H_ + hid, hn);
      }
      __syncthreads();   // drains sc1 h1 stores
      if (tid == 0) cohstorew(&h1flag[(rt & 7)*32 + ct], (u32)(step+1));
    }

    // ============ Phase B (b<256): LSTM2 split owner/helper1 ============
    if (isAB){
      if (tid < 32){
        while (cohloadw(&h1flag[(n >> 4)*32 + tid]) < (u32)(step+1)) __builtin_amdgcn_s_sleep(1);
      }
      __syncthreads();
      xs[tid]       = cohloadf(h1nxt + (size_t)n*H_ + tid);
      xs[256 + tid] = cohloadf(h1nxt + (size_t)n*H_ + 256 + tid);
      if (tid < 128) xs[512 + tid] = h2_keep[tid];
      __syncthreads();

      { // coalesced GEMV: 4 waves K-split, lane owns 4 gate-cols
        const int kw = tid >> 6, cl = tid & 63;
        const float* Wt = W2T + (size_t)kw*160*256 + cl*4;
        const float* xk = xs + kw*160;
        f4v acc = {0.f,0.f,0.f,0.f};
        #pragma unroll 4
        for (int k = 0; k < 160; ++k)
          acc += xk[k] * *(const f4v*)(Wt + (size_t)k*256);
        ((f4v*)(G2p + kw*256))[cl] = acc;
      }
      __syncthreads();
      G2[tid] = G2p[tid] + G2p[256+tid] + G2p[512+tid] + G2p[768+tid] + b2[tid];
      __syncthreads();
      if (tid < 64){
        const int unit = owner ? tid : (64 + tid);
        float gi = G2[tid], gf = G2[64+tid], gg = G2[128+tid], go = G2[192+tid];
        float cold = c2_keep[tid];
        float cn = sigf(gf)*cold + sigf(gi)*tanhf(gg);
        float hn = sigf(go)*tanhf(cn);
        c2_keep[tid] = cn;
        cohstoref(h2p + (size_t)n*128 + unit, hn);
      }
      __syncthreads();                              // drain sc1 half stores
      if (tid == 0){
        cohstorew(owner ? &h2of[n] : &h2hf[n], (u32)(step+1));
        u32* of = owner ? &h2hf[n] : &h2of[n];
        while (cohloadw(of) < (u32)(step+1)) __builtin_amdgcn_s_sleep(1);
      }
      __syncthreads();
      if (tid < 128){
        float hv = cohloadf(h2p + (size_t)n*128 + tid);
        h2s[tid] = hv; h2_keep[tid] = hv;
      }
      __syncthreads();
    } else {
      // pure helpers: wait for both h2 halves, then load
      if (tid == 0){
        while (cohloadw(&h2of[n]) < (u32)(step+1)) __builtin_amdgcn_s_sleep(1);
        while (cohloadw(&h2hf[n]) < (u32)(step+1)) __builtin_amdgcn_s_sleep(1);
      }
      __syncthreads();
      if (tid < 128) h2s[tid] = cohloadf(h2p + (size_t)n*128 + tid);
      __syncthreads();
    }

    // ============ Phase C: attention split + (owner) merge/output ============
    {
      // energies: 16-lane group per t, 2-row pipelined
      const float4* h2f = (const float4*)h2s;
      const int grp = tid >> 4, gj = tid & 15;
      const float4 hq0 = h2f[gj*2], hq1 = h2f[gj*2+1];
      int t = lo + grp;
      for (; t + 16 < hi; t += 32){
        const float4* kp0 = (const float4*)(krow + (size_t)t*kstr + gj*8);
        const float4* kp1 = (const float4*)(krow + (size_t)(t+16)*kstr + gj*8);
        float4 a0 = kp0[0], a1 = kp0[1], b0v = kp1[0], b1v = kp1[1];
        float e0 = dot4(a0,hq0) + dot4(a1,hq1);
        float e1 = dot4(b0v,hq0) + dot4(b1v,hq1);
        e0 += __shfl_xor(e0, 1); e1 += __shfl_xor(e1, 1);
        e0 += __shfl_xor(e0, 2); e1 += __shfl_xor(e1, 2);
        e0 += __shfl_xor(e0, 4); e1 += __shfl_xor(e1, 4);
        e0 += __shfl_xor(e0, 8); e1 += __shfl_xor(e1, 8);
        if (gj == 0){ Es[t] = e0; Es[t+16] = e1; }
      }
      for (; t < hi; t += 16){
        const float4* kp = (const float4*)(krow + (size_t)t*kstr + gj*8);
        float e = dot4(kp[0], hq0) + dot4(kp[1], hq1);
        e += __shfl_xor(e, 1); e += __shfl_xor(e, 2);
        e += __shfl_xor(e, 4); e += __shfl_xor(e, 8);
        if (gj == 0) Es[t] = e;
      }
      __syncthreads();
      // local max
      float lm = -3.0e38f;
      for (int tt = lo + tid; tt < hi; tt += 256) lm = fmaxf(lm, Es[tt]);
      #pragma unroll
      for (int off = 32; off > 0; off >>= 1) lm = fmaxf(lm, __shfl_xor(lm, off));
      if (lane == 0) red[qw] = lm;
      __syncthreads();
      const float m_l = fmaxf(fmaxf(red[0], red[1]), fmaxf(red[2], red[3]));
      __syncthreads();
      // exp + local sum
      float ls = 0.f;
      for (int tt = lo + tid; tt < hi; tt += 256){ float p = expf(Es[tt]-m_l); Es[tt] = p; ls += p; }
      #pragma unroll
      for (int off = 32; off > 0; off >>= 1) ls += __shfl_xor(ls, off);
      if (lane == 0) red[qw] = ls;
      __syncthreads();
      const float s_l = red[0] + red[1] + red[2] + red[3];
      // unnormalized ctx partial (coalesced half-wave rows, 4-deep)
      { const int part = tid >> 5, v4i = (tid & 31)*4;
        f4v a0 = {0.f,0.f,0.f,0.f}, a1 = a0, a2 = a0, a3 = a0;
        int tc = lo + part;
        for (; tc + 24 < hi; tc += 32){
          float p0 = Es[tc], p1 = Es[tc+8], p2 = Es[tc+16], p3 = Es[tc+24];
          f4v u0 = *(const f4v*)(vrow + (size_t)(tc    )*kstr + v4i);
          f4v u1 = *(const f4v*)(vrow + (size_t)(tc+ 8 )*kstr + v4i);
          f4v u2 = *(const f4v*)(vrow + (size_t)(tc+16 )*kstr + v4i);
          f4v u3 = *(const f4v*)(vrow + (size_t)(tc+24 )*kstr + v4i);
          a0 += p0*u0; a1 += p1*u1; a2 += p2*u2; a3 += p3*u3;
        }
        for (; tc < hi; tc += 8){
          f4v u0 = *(const f4v*)(vrow + (size_t)tc*kstr + v4i);
          a0 += Es[tc]*u0;
        }
        f4v ctv = a0 + a1 + a2 + a3;
        Cs[part*128 + v4i+0]=ctv.x; Cs[part*128 + v4i+1]=ctv.y;
        Cs[part*128 + v4i+2]=ctv.z; Cs[part*128 + v4i+3]=ctv.w;
      }
      __syncthreads();
      if (tid < 128){
        float s = 0.f;
        #pragma unroll
        for (int p8 = 0; p8 < 8; ++p8) s += Cs[p8*128 + tid];
        ctxL[tid] = s;
      }
      __syncthreads();

      if (roleIdx != 0){
        const int hs = roleIdx - 1;
        if (tid < 128) cohstoref(pctx + (size_t)hs*16384 + (size_t)n*128 + tid, ctxL[tid]);
        if (tid == 0){ cohstoref(pms + hs*256 + 2*n, m_l); cohstoref(pms + hs*256 + 2*n + 1, s_l); }
        __syncthreads();                            // drain sc1 stores
        if (tid == 0) cohstorew(&pflag[hs*128 + n], (u32)(step+1));
      } else {
        if (tid == 0){
          for (int hs = 0; hs < nsplit-1; ++hs){
            while (cohloadw(&pflag[hs*128 + n]) < (u32)(step+1)) __builtin_amdgcn_s_sleep(1);
          }
        }
        __syncthreads();
        if (tid < 128){
          float m = m_l;
          for (int hs = 0; hs < nsplit-1; ++hs)
            m = fmaxf(m, cohloadf(pms + hs*256 + 2*n));
          float e0 = expf(m_l - m);
          float denom = e0*s_l;
          float cacc  = e0*ctxL[tid];
          for (int hs = 0; hs < nsplit-1; ++hs){
            float mh = cohloadf(pms + hs*256 + 2*n);
            float sh = cohloadf(pms + hs*256 + 2*n + 1);
            float ch = cohloadf(pctx + (size_t)hs*16384 + (size_t)n*128 + tid);
            float e = expf(mh - m);
            denom += e*sh; cacc += e*ch;
          }
          Zs[tid]       = h2s[tid];
          Zs[128 + tid] = cacc / denom;
        }
        __syncthreads();
        { // output GEMM: transposed Wo2, 4-wave K-split
          const int kw = tid >> 6, lv = tid & 63;
          const float* wp = Wo2 + (size_t)kw*64*64 + lv;
          const float* zk = Zs + kw*64;
          float a = 0.f;
          #pragma unroll 8
          for (int k = 0; k < 64; ++k) a += zk[k]*wp[(size_t)k*64];
          Prp[kw*64 + lv] = a;
        }
        __syncthreads();
        if (tid < 64){
          float s = Prp[tid] + Prp[64+tid] + Prp[128+tid] + Prp[192+tid];
          float av = (tid < V_) ? (s + b_out[tid]) : -3.0e38f;
          if (tid < V_) out[((size_t)n*MAXLEN + step)*V_ + tid] = av;
          float bv = av; int bi = tid;
          #pragma unroll
          for (int off = 32; off > 0; off >>= 1){
            float ov = __shfl_xor(bv, off);
            int   oi = __shfl_xor(bi, off);
            if (ov > bv || (ov == bv && oi < bi)){ bv = ov; bi = oi; }
          }
          if (tid == 0) cohstorew(&tokflag[n], ((u32)(step+1) << 8) | (u32)bi);
        }
      }
    }
    __syncthreads();   // protect smem reuse by next step's Phase A
    float* tp = h1cur; h1cur = h1nxt; h1nxt = tp;
  }
}

extern "C" void kernel_launch(void* const* d_in, const int* in_sizes, int n_in,
                              void* d_out, int out_size, void* d_ws, size_t ws_size,
                              hipStream_t stream)
{
  const float* key    = (const float*)d_in[0];
  const float* val    = (const float*)d_in[1];
  const int*   lens   = (const int*)d_in[2];
  const float* emb    = (const float*)d_in[3];
  const float* W_ih1  = (const float*)d_in[4];
  const float* W_hh1  = (const float*)d_in[5];
  const float* b_ih1  = (const float*)d_in[6];
  const float* b_hh1  = (const float*)d_in[7];
  const float* W_ih2  = (const float*)d_in[8];
  const float* W_hh2  = (const float*)d_in[9];
  const float* b_ih2  = (const float*)d_in[10];
  const float* b_hh2  = (const float*)d_in[11];
  const float* W_out  = (const float*)d_in[12];
  const float* b_out  = (const float*)d_in[13];

  (void)in_sizes; (void)n_in; (void)out_size;

  (void)hipMemsetAsync(d_ws, 0, 8192, stream);   // all flags + pms
  prep_state<<<128, 256, 0, stream>>>(val, (char*)d_ws);
  prep_embG<<<280, 256, 0, stream>>>(emb, W_ih1, (char*)d_ws);
  prep_vmG<<<1024, 256, 0, stream>>>(W_ih1, b_ih1, b_hh1, (char*)d_ws);
  prep_W1p<<<256, 256, 0, stream>>>(W_hh1, (char*)d_ws);
  prep_W2T<<<640, 256, 0, stream>>>(W_ih2, W_hh2, b_ih2, b_hh2, (char*)d_ws);
  prep_Wo2<<<64, 256, 0, stream>>>(W_out, (char*)d_ws);

  const int use_t = (ws_size >= WS_T_NEED) ? 1 : 0;
  const float* keyA = key; const float* valA = val;
  ull nstr = (ull)KS_, kstr = (ull)N_*KS_;
  if (use_t){
    prep_transpose<<<2048, 256, 0, stream>>>(key, val, (char*)d_ws);
    keyA = (const float*)((char*)d_ws + OFF_KT);
    valA = (const float*)((char*)d_ws + OFF_VT);
    nstr = (ull)T_*KS_; kstr = (ull)KS_;
  }

  // Deadlock safety: only launch the 4-way (512-block) pipeline if the
  // occupancy calculator guarantees 2 blocks/CU co-residency; otherwise
  // fall back to the proven 256-block 2-way split.
  int maxb = 0;
  (void)hipOccupancyMaxActiveBlocksPerMultiprocessor(&maxb, decoder_main, 256, 0);
  const int nsplit = (maxb >= 2) ? 4 : 2;
  const int grid   = (nsplit == 4) ? 512 : 256;

  decoder_main<<<grid, 256, 0, stream>>>(
      keyA, valA, nstr, kstr, nsplit, lens, b_out,
      (float*)d_out, (char*)d_ws);
}